// Round 10
// baseline (125.474 us; speedup 1.0000x reference)
//
#include <hip/hip_runtime.h>
#include <hip/hip_bf16.h>

// GQA causal attention fwd: B=1, H=16, HKV=4, S=2048, D=128, fp32 in/out.
// Round 10 (resubmit of r9; broker timeout): T4 counted-vmcnt pipeline.
// K 3-ring + V 2-ring (80KB LDS, 2 blocks/CU), two raw s_barriers/tile with
// hand-counted s_waitcnt vmcnt(N) (never a mid-loop full drain). Otherwise
// identical to r8: 32x32x16 MFMA, swapped QK^T and swapped PV, in-register
// P via cvt_pk+permlane32_swap, T13 defer-rescale, split-kv merge epilogue.

#define NH    16
#define NHKV  4
#define SEQ   2048
#define DIM   128
#define QBLK  64
#define KVBLK 64
#define NT    (SEQ / KVBLK)   // 32 kv tiles

typedef __attribute__((ext_vector_type(8)))  short bf16x8_t;
typedef __attribute__((ext_vector_type(16))) float f32x16_t;

__device__ inline ushort f2bf(float f) {
    uint x = __float_as_uint(f);
    uint r = (x + 0x7fffu + ((x >> 16) & 1u)) >> 16;
    return (ushort)r;
}

__device__ inline uint cvtpk_bf16(float lo, float hi) {
    uint r;
    asm("v_cvt_pk_bf16_f32 %0, %1, %2" : "=v"(r) : "v"(lo), "v"(hi));
    return r;
}

#define GLOAD_LDS16(gsrc, ldst) \
    __builtin_amdgcn_global_load_lds( \
        (const __attribute__((address_space(1))) void*)(gsrc), \
        (__attribute__((address_space(3))) void*)(ldst), 16, 0, 0)

#define WAITV(n) asm volatile("s_waitcnt vmcnt(" #n ")" ::: "memory")

// ---- prep: K -> bf16 swizzled [kvh][tile][kv*256 + d*2 ^ ((kv&7)<<4)],
//            V -> bf16 transposed swizzled [kvh][tile][d*128 + kv*2 ^ ((d&7)<<4)]
extern "C" __global__ __launch_bounds__(256)
void prep_kv(const float* __restrict__ K, const float* __restrict__ V,
             ushort* __restrict__ Kpre, ushort* __restrict__ Vpre)
{
    int gid = blockIdx.x * 256 + threadIdx.x;
    if (blockIdx.x < 1024) {
        int kvh = gid >> 16; int rem = gid & 65535;
        int s = rem >> 5; int dq = (rem & 31) << 2;
        float4 f = *(const float4*)(K + ((size_t)(kvh * SEQ + s)) * DIM + dq);
        uint lo = (uint)f2bf(f.x) | ((uint)f2bf(f.y) << 16);
        uint hi = (uint)f2bf(f.z) | ((uint)f2bf(f.w) << 16);
        int tile = s >> 6, row = s & 63;
        uint byte = ((uint)(row * 256 + dq * 2)) ^ ((uint)(row & 7) << 4);
        *(uint2*)((char*)Kpre + (((size_t)(kvh * NT + tile)) << 14) + byte) =
            make_uint2(lo, hi);
    } else {
        int g2 = gid - 1024 * 256;
        int kvh = g2 >> 16; int rem = g2 & 65535;
        int d = rem & 127; int t2 = rem >> 7;
        int tile = t2 >> 4; int kv = (t2 & 15) << 2;
        const float* b = V + ((size_t)(kvh * SEQ + tile * 64 + kv)) * DIM + d;
        uint lo = (uint)f2bf(b[0])       | ((uint)f2bf(b[DIM]) << 16);
        uint hi = (uint)f2bf(b[2 * DIM]) | ((uint)f2bf(b[3 * DIM]) << 16);
        uint byte = ((uint)(d * 128 + kv * 2)) ^ ((uint)(d & 7) << 4);
        *(uint2*)((char*)Vpre + (((size_t)(kvh * NT + tile)) << 14) + byte) =
            make_uint2(lo, hi);
    }
}

extern "C" __global__ __launch_bounds__(256, 2)
void attn_fwd(const float* __restrict__ Q, const ushort* __restrict__ Kpre,
              const ushort* __restrict__ Vpre, float* __restrict__ O)
{
    // pair heavy with light: CU hosting blocks b and b+256 gets qt=p and 31-p
    const int bid = blockIdx.x;
    const int h   = bid & 15;
    const int p   = bid >> 4;                 // 0..31
    const int qt  = (p < 16) ? p : 47 - p;
    const int kvh = h >> 2;                   // gqa_group_size = 4
    const int q0  = qt * QBLK;
    const int tid  = threadIdx.x;
    const int w    = tid >> 6;
    const int qh   = w >> 1;      // q-half   (0: q[0:32), 1: q[32:64))
    const int kh   = w & 1;       // kv-half  (0: kv[0:32), 1: kv[32:64))
    const int lane = tid & 63;
    const int q31  = lane & 31;
    const int hi   = lane >> 5;

    // [K ring: 3 x 16KB][V ring: 2 x 16KB] = 80KB; merge epilogue aliases it
    __shared__ char smem[81920];
    char* smb = &smem[0];

    const float qscale = 0.08838834764831845f * 1.4426950408889634f; // 1/sqrt(D)*log2e

    // ---- Q fragments: B-frag of swapped QK^T (col = q = lane&31, k = hi*8+i)
    bf16x8_t qf[8];
    const int qrow = q0 + qh * 32 + q31;
    {
        const float* qp = Q + ((size_t)h * SEQ + qrow) * DIM + hi * 8;
#pragma unroll
        for (int ks = 0; ks < 8; ++ks) {
            float4 f0 = *(const float4*)(qp + ks * 16);
            float4 f1 = *(const float4*)(qp + ks * 16 + 4);
            bf16x8_t a;
            a[0] = (short)f2bf(f0.x * qscale); a[1] = (short)f2bf(f0.y * qscale);
            a[2] = (short)f2bf(f0.z * qscale); a[3] = (short)f2bf(f0.w * qscale);
            a[4] = (short)f2bf(f1.x * qscale); a[5] = (short)f2bf(f1.y * qscale);
            a[6] = (short)f2bf(f1.z * qscale); a[7] = (short)f2bf(f1.w * qscale);
            qf[ks] = a;
        }
    }

    // O^T accumulator: 4 d-tiles (d = m*32 + crow), col = q = lane&31
    f32x16_t oacc[4];
#pragma unroll
    for (int m = 0; m < 4; ++m)
#pragma unroll
        for (int i = 0; i < 16; ++i) oacc[m][i] = 0.f;
    float m_r = -1e30f, l_r = 0.f;   // per-lane softmax state for q = lane&31

    const size_t kvbase = (size_t)kvh * NT;
    const int nt = qt + 1;

    auto stageK = [&](int slot, int t) {   // 4 loads
        const char* kg = (const char*)Kpre + ((kvbase + t) << 14) + tid * 16;
        char* kl = smb + slot * 16384 + tid * 16;
#pragma unroll
        for (int c = 0; c < 4; ++c) GLOAD_LDS16(kg + c * 4096, kl + c * 4096);
    };
    auto stageV = [&](int slot, int t) {   // 4 loads
        const char* vg = (const char*)Vpre + ((kvbase + t) << 14) + tid * 16;
        char* vl = smb + 49152 + slot * 16384 + tid * 16;
#pragma unroll
        for (int c = 0; c < 4; ++c) GLOAD_LDS16(vg + c * 4096, vl + c * 4096);
    };

    // ---- prologue: issue K(0), K(1), V(0) (FIFO order matters for waits) ----
    stageK(0, 0);
    if (nt >= 2) stageK(1, 1);
    stageV(0, 0);

    const int  kvrow = kh * 32 + q31;              // A-frag row of K (kv)
    const uint kswz  = ((uint)(kvrow & 7)) << 4;

    int kcur = 0;   // K ring slot of tile t

    for (int t = 0; t < nt; ++t) {
        const bool diag = (t == nt - 1);
        const bool active = !(diag && w == 1);  // (qh=0,kh=1) fully masked

        // ---- W1 + barrier1: K(t) staged & visible; buffers reusable ----
        if (t == nt - 1) { WAITV(4); } else { WAITV(8); }
        __builtin_amdgcn_s_barrier();
        __builtin_amdgcn_sched_barrier(0);

        // ---- issue next stages (V depth-1, K depth-2), FIFO: V then K ----
        if (t + 1 < nt) stageV((t + 1) & 1, t + 1);
        if (t + 2 < nt) { int k2 = kcur + 2 >= 3 ? kcur - 1 : kcur + 2; stageK(k2, t + 2); }

        f32x16_t sacc;
        float pv[16];
        bf16x8_t pa[2];
        if (active) {
            // ---- swapped QK^T: S^T[kv][q], one 32x32 tile per wave ----
#pragma unroll
            for (int i = 0; i < 16; ++i) sacc[i] = 0.f;
            const char* kb = smb + kcur * 16384;
            __builtin_amdgcn_s_setprio(1);
#pragma unroll
            for (int ks = 0; ks < 8; ++ks) {
                uint byte = ((uint)(kvrow * 256 + ks * 32 + hi * 16)) ^ kswz;
                bf16x8_t kf = *(bf16x8_t*)(kb + byte);
                sacc = __builtin_amdgcn_mfma_f32_32x32x16_bf16(kf, qf[ks], sacc, 0, 0, 0);
            }
            __builtin_amdgcn_s_setprio(0);

            // ---- causal mask on the diagonal sub-tile (kh == qh waves) ----
            if (diag && (w == 0 || w == 3)) {
#pragma unroll
                for (int reg = 0; reg < 16; ++reg) {
                    int crow = (reg & 3) + 8 * (reg >> 2) + 4 * hi;   // kv-local
                    if (crow > q31) sacc[reg] = -1e30f;
                }
            }

            // ---- per-lane row max ----
            float pmax = sacc[0];
#pragma unroll
            for (int i = 1; i < 16; ++i) pmax = fmaxf(pmax, sacc[i]);
            pmax = fmaxf(pmax, __shfl_xor(pmax, 32, 64));

            // ---- T13 defer-rescale (exp2 domain, THR = 8) ----
            if (!__all(pmax - m_r <= 8.f)) {
                float mnew = fmaxf(m_r, pmax);
                float alpha = __builtin_exp2f(m_r - mnew);
                m_r = mnew;
                l_r *= alpha;
#pragma unroll
                for (int m = 0; m < 4; ++m)
#pragma unroll
                    for (int i = 0; i < 16; ++i) oacc[m][i] *= alpha;
            }

            // ---- P = exp2(S - m) ----
            float psum = 0.f;
#pragma unroll
            for (int i = 0; i < 16; ++i) {
                pv[i] = __builtin_exp2f(sacc[i] - m_r);
                psum += pv[i];
            }
            psum += __shfl_xor(psum, 32, 64);
            l_r += psum;

            // ---- T12: P -> PV B-frags via cvt_pk + permlane32_swap ----
#pragma unroll
            for (int hf = 0; hf < 2; ++hf) {
                uint a0 = cvtpk_bf16(pv[hf * 8 + 0], pv[hf * 8 + 1]);
                uint a1 = cvtpk_bf16(pv[hf * 8 + 2], pv[hf * 8 + 3]);
                uint b0 = cvtpk_bf16(pv[hf * 8 + 4], pv[hf * 8 + 5]);
                uint b1 = cvtpk_bf16(pv[hf * 8 + 6], pv[hf * 8 + 7]);
                asm volatile("v_permlane32_swap_b32 %0, %1" : "+v"(a0), "+v"(b0));
                asm volatile("v_permlane32_swap_b32 %0, %1" : "+v"(a1), "+v"(b1));
                uint4 tmp = make_uint4(a0, a1, b0, b1);
                pa[hf] = *(bf16x8_t*)&tmp;
            }
        }

        // ---- W2 + barrier2: V(t) staged & visible (counted, no full drain) ----
        if (t == 0) {
            if (nt >= 3) { WAITV(8); } else if (nt == 2) { WAITV(4); } else { WAITV(0); }
        } else {
            if (t + 2 < nt) { WAITV(12); } else if (t + 1 < nt) { WAITV(8); } else { WAITV(0); }
        }
        __builtin_amdgcn_s_barrier();
        __builtin_amdgcn_sched_barrier(0);

        if (active) {
            // ---- swapped PV: O^T[d][q] += V^T[d][kv] P^T[kv][q] ----
            const char* vb = smb + 49152 + (t & 1) * 16384;
            __builtin_amdgcn_s_setprio(1);
#pragma unroll
            for (int m = 0; m < 4; ++m) {
                const int drow = m * 32 + q31;
                const uint vswz = ((uint)(drow & 7)) << 4;
#pragma unroll
                for (int ks2 = 0; ks2 < 2; ++ks2) {
                    uint byte = ((uint)(drow * 128 + kh * 64 + ks2 * 32 + hi * 16)) ^ vswz;
                    bf16x8_t vf = *(bf16x8_t*)(vb + byte);
                    oacc[m] = __builtin_amdgcn_mfma_f32_32x32x16_bf16(vf, pa[ks2], oacc[m], 0, 0, 0);
                }
            }
            __builtin_amdgcn_s_setprio(0);
        }

        kcur = (kcur + 1 == 3) ? 0 : kcur + 1;
    }

    // ---- split-kv merge (kh=1 -> LDS, kh=0 merges + writes out) ----
    __syncthreads();                  // everyone done with ring buffers
    float* fb  = (float*)smb;         // m/l: [qh][2][32]
    float* fb2 = fb + 128;            // O^T: [qh][d=128][q=32] = 32KB
    if (kh == 1) {
        if (hi == 0) { fb[qh * 64 + q31] = m_r; fb[qh * 64 + 32 + q31] = l_r; }
#pragma unroll
        for (int m = 0; m < 4; ++m)
#pragma unroll
            for (int reg = 0; reg < 16; ++reg) {
                int d = m * 32 + (reg & 3) + 8 * (reg >> 2) + 4 * hi;
                fb2[(qh * 128 + d) * 32 + q31] = oacc[m][reg];
            }
    }
    __syncthreads();
    if (kh == 0) {
        float m1 = fb[qh * 64 + q31];
        float l1 = fb[qh * 64 + 32 + q31];
        float mN = fmaxf(m_r, m1);
        float a0 = __builtin_exp2f(m_r - mN);
        float a1 = __builtin_exp2f(m1 - mN);
        float inv = 1.0f / (l_r * a0 + l1 * a1);
        a0 *= inv; a1 *= inv;
        float* op = O + ((size_t)h * SEQ + qrow) * DIM;
#pragma unroll
        for (int m = 0; m < 4; ++m)
#pragma unroll
            for (int rq = 0; rq < 4; ++rq) {
                int d0 = m * 32 + 8 * rq + 4 * hi;
                float4 v;
                v.x = oacc[m][rq * 4 + 0] * a0 + fb2[(qh * 128 + d0 + 0) * 32 + q31] * a1;
                v.y = oacc[m][rq * 4 + 1] * a0 + fb2[(qh * 128 + d0 + 1) * 32 + q31] * a1;
                v.z = oacc[m][rq * 4 + 2] * a0 + fb2[(qh * 128 + d0 + 2) * 32 + q31] * a1;
                v.w = oacc[m][rq * 4 + 3] * a0 + fb2[(qh * 128 + d0 + 3) * 32 + q31] * a1;
                *(float4*)(op + d0) = v;
            }
    }
}

extern "C" void kernel_launch(void* const* d_in, const int* in_sizes, int n_in,
                              void* d_out, int out_size, void* d_ws, size_t ws_size,
                              hipStream_t stream) {
    const float* Q = (const float*)d_in[0];
    const float* K = (const float*)d_in[1];
    const float* V = (const float*)d_in[2];
    float* O = (float*)d_out;
    ushort* Kpre = (ushort*)d_ws;                          // 2 MB
    ushort* Vpre = (ushort*)((char*)d_ws + (2u << 20));    // 2 MB
    prep_kv<<<2048, 256, 0, stream>>>(K, V, Kpre, Vpre);
    attn_fwd<<<dim3(512), 256, 0, stream>>>(Q, Kpre, Vpre, O);
}